// Round 22
// baseline (103.614 us; speedup 1.0000x reference)
//
#include <hip/hip_runtime.h>

// Problem constants: features [C=32, N], coords [N,3]=(b,h,w),
// output [B=64, C=32, NH=64, NW=256] float32.
#define CC 32
#define BB 64
#define NHH 64
#define NWW 256
#define PLANE (NHH * NWW)        // 16384 cells per batch
#define BSTRIDE (CC * PLANE)     // 524288 floats per batch in out
#define NCELLS (BB * PLANE)      // 1048576 total cells
#define TN 512                   // K2 tile: 512 n x 32 c (f16)
#define LSTR 520                 // K2 LDS row stride in f16 units (512 + 8 pad)

typedef float f32x4 __attribute__((ext_vector_type(4)));
typedef _Float16 f16x8 __attribute__((ext_vector_type(8)));  // 16B

// ---------- Fallback (round-1) direct scatter ----------
__global__ void pss_scatter_direct(const float* __restrict__ features,
                                   const int* __restrict__ coords,
                                   float* __restrict__ out, int N) {
    int n = blockIdx.x * blockDim.x + threadIdx.x;
    if (n >= N) return;
    int b = coords[3 * n + 0];
    int h = coords[3 * n + 1];
    int w = coords[3 * n + 2];
    int base = b * BSTRIDE + h * NWW + w;
#pragma unroll
    for (int c = 0; c < CC; ++c)
        out[base + c * PLANE] = features[c * N + n];
}

// ---------- K-1: zero invmap ----------
__global__ __launch_bounds__(256) void pss_zero(int4* __restrict__ p, int n4) {
    int i = blockIdx.x * blockDim.x + threadIdx.x;
    if (i < n4) p[i] = make_int4(0, 0, 0, 0);
}

// ---------- K1: sequential convert f32->f16 (+ fused invmap scatter) ----------
// features [C][N] f32 -> featC [C][N] f16. PURE COPY SHAPE: both streams
// sequential (the only pattern measured at 6.3-7 TB/s this session).
// N % 8 == 0, so 8-float units never cross channel rows; featC layout is
// identical to features, just f16. Grid-stride, 2048 blocks (G11).
__global__ __launch_bounds__(256) void pss_convert_f16(
        const float* __restrict__ features, const int* __restrict__ coords,
        f16x8* __restrict__ featC, int* __restrict__ invmap, int N, int units) {
    const int nthreads = gridDim.x * 256;
    const int gtid = blockIdx.x * 256 + threadIdx.x;

    // Fused invmap scatter (random 4B into 4MB region; L3-absorbed).
    for (int n = gtid; n < N; n += nthreads) {
        int b = coords[3 * n + 0];
        int h = coords[3 * n + 1];
        int w = coords[3 * n + 2];
        invmap[b * PLANE + h * NWW + w] = n + 1;
    }

    // Sequential convert: unit i = floats [8i, 8i+8).
    for (int i = gtid; i < units; i += nthreads) {
        const float* src = features + (size_t)i * 8;
        f32x4 a = *(const f32x4*)src;
        f32x4 b = *(const f32x4*)(src + 4);
        f16x8 hv;
        hv[0] = (_Float16)a.x; hv[1] = (_Float16)a.y;
        hv[2] = (_Float16)a.z; hv[3] = (_Float16)a.w;
        hv[4] = (_Float16)b.x; hv[5] = (_Float16)b.y;
        hv[6] = (_Float16)b.z; hv[7] = (_Float16)b.w;
        featC[i] = hv;  // lanes contiguous, 1KB/instr, sequential
    }
}

// ---------- K2: f16 transpose featC [C][N] -> featT [N][C] ----------
// Reads are strided (1KB per channel-row visit) but from a 57.6MB buffer
// JUST WRITTEN by K1 -> L3-resident. Writes sequential. If the session's
// 2.9 TB/s plateau is DRAM-side, this pass escapes it (the diagnostic:
// FETCH_SIZE ~ 0 and dur ~15us).
//   Load : DMA global->LDS, row c = 1KB (512 f16), dest wave-uniform base +
//          lane*16B = lds16[c*LSTR + 8*lane].
//   Store: b32 units, lanes contiguous 1KB/instr, sequential in n.
//   LDS  : b32-pair reads (bank = (4e + nlp)%32, 4-way max - minor).
__global__ __launch_bounds__(256) void pss_transpose_f16f16(
        const _Float16* __restrict__ featC, f16x8* __restrict__ featT, int N) {
    __shared__ _Float16 lds16[CC * LSTR];  // 33280 B

    int t = threadIdx.x;
    int lane = t & 63;
    int w = t >> 6;
    int n0 = blockIdx.x * TN;

    if (n0 + TN <= N) {
#pragma unroll
        for (int r = 0; r < 8; ++r) {
            int c = 8 * w + r;
            const _Float16* gp = &featC[(size_t)c * N + n0 + 8 * lane];
            __builtin_amdgcn_global_load_lds(
                (const __attribute__((address_space(1))) void*)gp,
                (__attribute__((address_space(3))) void*)&lds16[c * LSTR],
                16, 0, 0);
        }
    } else {
        // Tail tile (N % 8 == 0 -> clean 8-granule guard).
#pragma unroll
        for (int r = 0; r < 8; ++r) {
            int c = 8 * w + r;
            int nn = n0 + 8 * lane;
            f16x8 v = {};
            if (nn < N) v = *(const f16x8*)&featC[(size_t)c * N + nn];
            *(f16x8*)&lds16[c * LSTR + 8 * lane] = v;
        }
    }

    __syncthreads();  // drains vmcnt(0): DMA complete

    // Store phase: pair p covers output units (g, 2*nlp) and (g, 2*nlp+1).
    // b32 read = f16 pair (nl, nl+1) of channel 8g+e.
#pragma unroll
    for (int j = 0; j < 4; ++j) {
        int p = t + 256 * j;       // 0..1023
        int g = p & 3;             // channel group of 8
        int nlp = p >> 2;          // 0..255 -> nl = 2*nlp, 2*nlp+1
        int nl0 = 2 * nlp;
        if (n0 + nl0 < N) {
            unsigned r[8];
#pragma unroll
            for (int e = 0; e < 8; ++e)
                r[e] = *(const unsigned*)&lds16[(8 * g + e) * LSTR + nl0];
            unsigned lo[4], hi[4];
#pragma unroll
            for (int k = 0; k < 4; ++k) {
                lo[k] = (r[2 * k] & 0xffffu) | (r[2 * k + 1] << 16);
                hi[k] = (r[2 * k] >> 16) | (r[2 * k + 1] & 0xffff0000u);
            }
            // units: (n0+nl0)*4 + g  and  (n0+nl0+1)*4 + g
            unsigned* d0 = (unsigned*)&featT[((size_t)n0 + nl0) * 4 + g];
            d0[0] = lo[0]; d0[1] = lo[1]; d0[2] = lo[2]; d0[3] = lo[3];
            if (n0 + nl0 + 1 < N) {
                unsigned* d1 = (unsigned*)&featT[((size_t)n0 + nl0 + 1) * 4 + g];
                d1[0] = hi[0]; d1[1] = hi[1]; d1[2] = hi[2]; d1[3] = hi[3];
            }
        }
    }
}

// ---------- K3: gather f16 featT rows per cell, emit out coalesced ----------
__global__ __launch_bounds__(256) void pss_gather_emit_f16(
        const f16x8* __restrict__ featT, const int* __restrict__ invmap,
        float* __restrict__ out) {
    __shared__ float lds[NWW * (CC + 1)];  // 256 * 33 floats

    int row = blockIdx.x;          // 0 .. B*NH-1  (row = b*NHH + h)
    int b = row / NHH;
    int h = row % NHH;
    int t = threadIdx.x;           // 0..255 = w

    int inv = invmap[(size_t)row * NWW + t];  // coalesced 1KB per block

    if (inv > 0) {
        const f16x8* src = featT + (size_t)(inv - 1) * 4;  // 64B row = 1 line
#pragma unroll
        for (int k = 0; k < 4; ++k) {
            f16x8 hv = src[k];
#pragma unroll
            for (int e = 0; e < 8; ++e)
                lds[t * (CC + 1) + 8 * k + e] = (float)hv[e];
        }
    } else {
#pragma unroll
        for (int k = 0; k < CC; ++k)
            lds[t * (CC + 1) + k] = 0.0f;
    }

    __syncthreads();

    size_t obase = (size_t)b * BSTRIDE + (size_t)h * NWW + t;
#pragma unroll
    for (int c = 0; c < CC; ++c) {
        float v = lds[t * (CC + 1) + c];  // bank (t+c)%32 -> conflict-free
        __builtin_nontemporal_store(v, &out[obase + (size_t)c * PLANE]);
    }
}

extern "C" void kernel_launch(void* const* d_in, const int* in_sizes, int n_in,
                              void* d_out, int out_size, void* d_ws, size_t ws_size,
                              hipStream_t stream) {
    const float* features = (const float*)d_in[0];
    const int* coords = (const int*)d_in[1];
    float* out = (float*)d_out;
    const int N = in_sizes[1] / 3;

    const size_t invmap_bytes = (size_t)NCELLS * sizeof(int);        // 4 MiB
    const size_t featC_bytes = (size_t)N * CC * sizeof(_Float16);    // ~57.6 MB
    const size_t featT_bytes = featC_bytes;                          // ~57.6 MB

    if (ws_size < invmap_bytes + featC_bytes + featT_bytes) {
        // Fallback: direct scatter (correct, slower).
        (void)hipMemsetAsync(d_out, 0, (size_t)out_size * sizeof(float), stream);
        int blocks = (N + 255) / 256;
        pss_scatter_direct<<<blocks, 256, 0, stream>>>(features, coords, out, N);
        return;
    }

    int* invmap = (int*)d_ws;
    _Float16* featC = (_Float16*)((char*)d_ws + invmap_bytes);
    f16x8* featT = (f16x8*)((char*)d_ws + invmap_bytes + featC_bytes);

    // Zero invmap (0 == empty cell).
    pss_zero<<<(NCELLS / 4 + 255) / 256, 256, 0, stream>>>((int4*)invmap,
                                                           NCELLS / 4);

    // K1: sequential f32->f16 convert (+invmap scatter). Grid-stride, 2048 blocks.
    int units = (N * CC) / 8;  // 3,600,000
    pss_convert_f16<<<2048, 256, 0, stream>>>(features, coords, (f16x8*)featC,
                                              invmap, N, units);

    // K2: f16 transpose (L3-hot strided reads, sequential writes).
    int tiles = (N + TN - 1) / TN;  // 1758
    pss_transpose_f16f16<<<tiles, 256, 0, stream>>>(featC, featT, N);

    // K3: gather + emit.
    pss_gather_emit_f16<<<BB * NHH, 256, 0, stream>>>(featT, invmap, out);
}

// Round 23
// 94.913 us; speedup vs baseline: 1.0917x; 1.0917x over previous
//
#include <hip/hip_runtime.h>

// Problem constants: features [C=32, N], coords [N,3]=(b,h,w),
// output [B=64, C=32, NH=64, NW=256] float32.
#define CC 32
#define BB 64
#define NHH 64
#define NWW 256
#define PLANE (NHH * NWW)        // 16384 cells per batch
#define BSTRIDE (CC * PLANE)     // 524288 floats per batch in out
#define NCELLS (BB * PLANE)      // 1048576 total cells
#define LROW 260                 // LDS row stride (dwords); 1040B rows, 16B-aligned
#define NXCD 8

typedef float f32x4 __attribute__((ext_vector_type(4)));
typedef _Float16 f16x8 __attribute__((ext_vector_type(8)));  // 16B

// Bijective XCD-chunked swizzle (m204): maps round-robin hardware placement
// (xcd = orig % 8) to contiguous per-XCD chunks. Valid for any nwg.
__device__ __forceinline__ int xcd_swizzle(int orig, int nwg) {
    int q = nwg / NXCD, r = nwg % NXCD;
    int xcd = orig % NXCD, pos = orig / NXCD;
    return (xcd < r ? xcd * (q + 1) : r * (q + 1) + (xcd - r) * q) + pos;
}

// ---------- Fallback (round-1) direct scatter ----------
__global__ void pss_scatter_direct(const float* __restrict__ features,
                                   const int* __restrict__ coords,
                                   float* __restrict__ out, int N) {
    int n = blockIdx.x * blockDim.x + threadIdx.x;
    if (n >= N) return;
    int b = coords[3 * n + 0];
    int h = coords[3 * n + 1];
    int w = coords[3 * n + 2];
    int base = b * BSTRIDE + h * NWW + w;
#pragma unroll
    for (int c = 0; c < CC; ++c)
        out[base + c * PLANE] = features[c * N + n];
}

// ---------- K1: DMA transpose -> f16 featT, fused UNINITIALIZED invmap ------
// features [C][N] f32 -> featT [N][C] f16; invmap[cell] = n (no zeroing:
// gather validates via back-pointer check, so garbage/poison is harmless).
// XCD-chunked swizzle: each XCD reads a contiguous ~1/8 n-chunk of the same
// 32 channel rows instead of 8 XCDs interleaving 1KB segments everywhere.
__global__ __launch_bounds__(256) void pss_transpose_f16_swz(
        const float* __restrict__ features, const int* __restrict__ coords,
        f16x8* __restrict__ featT, int* __restrict__ invmap, int N, int nwg) {
    __shared__ float lds[CC * LROW];  // 33280 B

    int t = threadIdx.x;
    int lane = t & 63;
    int w = t >> 6;
    int tile = xcd_swizzle(blockIdx.x, nwg);
    int n0 = tile * 256;

    // Fused invmap scatter (random 4B into 4MB region; L3-absorbed).
    int n = n0 + t;
    if (n < N) {
        int b = coords[3 * n + 0];
        int h = coords[3 * n + 1];
        int ww = coords[3 * n + 2];
        invmap[b * PLANE + h * NWW + ww] = n;
    }

    // Load phase: wave w owns channel rows c = 8w .. 8w+7.
    if (n0 + 256 <= N) {
        // Direct global->LDS DMA, 1KB per issue (r18-proven).
#pragma unroll
        for (int r = 0; r < 8; ++r) {
            int c = 8 * w + r;
            const float* gp = &features[(size_t)c * N + n0 + 4 * lane];
            __builtin_amdgcn_global_load_lds(
                (const __attribute__((address_space(1))) void*)gp,
                (__attribute__((address_space(3))) void*)&lds[c * LROW],
                16, 0, 0);
        }
    } else {
        // Tail tile: guarded path (N % 4 == 0 -> whole-quad guard).
#pragma unroll
        for (int r = 0; r < 8; ++r) {
            int c = 8 * w + r;
            int nn = n0 + 4 * lane;
            f32x4 v = (f32x4){0.f, 0.f, 0.f, 0.f};
            if (nn < N)
                v = *(const f32x4*)&features[(size_t)c * N + nn];
            *(f32x4*)&lds[c * LROW + 4 * lane] = v;
        }
    }

    __syncthreads();  // drains vmcnt(0): DMA complete, LDS visible

    // Store phase: transposed read + f16 pack + linear 16B store (r17-proven).
#pragma unroll
    for (int j = 0; j < 4; ++j) {
        int idx = t + 256 * j;
        int nl = idx >> 2;
        int g = idx & 3;
        if (n0 + nl < N) {
            f16x8 hv;
#pragma unroll
            for (int e = 0; e < 8; ++e)
                hv[e] = (_Float16)lds[(8 * g + e) * LROW + nl];
            featT[(size_t)n0 * 4 + idx] = hv;  // lanes contiguous, 1KB/instr
        }
    }
}

// ---------- K2: validated gather, emit out coalesced ----------
// invmap is UNINITIALIZED for empty cells (poison/garbage). Validation:
// inv must be in [0,N) AND coords[inv] must map back to exactly this cell.
// A real voxel's coords always map to an OCCUPIED cell, so any garbage value
// at an EMPTY cell can never pass the back-check; poison 0xAAAAAAAA fails the
// range check. Stale values across graph replays equal the rewritten values
// (same deterministic mapping) -> harmless.
__global__ __launch_bounds__(256) void pss_gather_emit_v(
        const f16x8* __restrict__ featT, const int* __restrict__ invmap,
        const int* __restrict__ coords, float* __restrict__ out, int N) {
    __shared__ float lds[NWW * (CC + 1)];  // 256 * 33 floats

    int row = xcd_swizzle(blockIdx.x, BB * NHH);  // 4096 rows, contiguous per XCD
    int b = row / NHH;
    int h = row % NHH;
    int t = threadIdx.x;           // 0..255 = w

    int cell = row * NWW + t;
    int inv = invmap[cell];        // coalesced 1KB per block

    bool valid = ((unsigned)inv < (unsigned)N);
    if (valid) {
        // Back-pointer check: 12B random read, coords is L3-resident (10.8MB).
        valid = (coords[3 * inv + 0] * PLANE + coords[3 * inv + 1] * NWW +
                 coords[3 * inv + 2]) == cell;
    }

    if (valid) {
        const f16x8* src = featT + (size_t)inv * 4;  // 64B row = 1 line
#pragma unroll
        for (int k = 0; k < 4; ++k) {
            f16x8 hv = src[k];
#pragma unroll
            for (int e = 0; e < 8; ++e)
                lds[t * (CC + 1) + 8 * k + e] = (float)hv[e];
        }
    } else {
#pragma unroll
        for (int k = 0; k < CC; ++k)
            lds[t * (CC + 1) + k] = 0.0f;
    }

    __syncthreads();

    size_t obase = (size_t)b * BSTRIDE + (size_t)h * NWW + t;
#pragma unroll
    for (int c = 0; c < CC; ++c) {
        float v = lds[t * (CC + 1) + c];  // bank (t+c)%32 -> conflict-free
        __builtin_nontemporal_store(v, &out[obase + (size_t)c * PLANE]);
    }
}

extern "C" void kernel_launch(void* const* d_in, const int* in_sizes, int n_in,
                              void* d_out, int out_size, void* d_ws, size_t ws_size,
                              hipStream_t stream) {
    const float* features = (const float*)d_in[0];
    const int* coords = (const int*)d_in[1];
    float* out = (float*)d_out;
    const int N = in_sizes[1] / 3;

    const size_t invmap_bytes = (size_t)NCELLS * sizeof(int);        // 4 MiB
    const size_t featT_bytes = (size_t)N * CC * sizeof(_Float16);    // ~57.6 MB

    if (ws_size < invmap_bytes + featT_bytes) {
        // Fallback: direct scatter (correct, slower).
        (void)hipMemsetAsync(d_out, 0, (size_t)out_size * sizeof(float), stream);
        int blocks = (N + 255) / 256;
        pss_scatter_direct<<<blocks, 256, 0, stream>>>(features, coords, out, N);
        return;
    }

    int* invmap = (int*)d_ws;
    f16x8* featT = (f16x8*)((char*)d_ws + invmap_bytes);

    // K1: transpose + invmap scatter (no zero pass needed — validated gather).
    int tiles = (N + 255) / 256;  // 3516
    pss_transpose_f16_swz<<<tiles, 256, 0, stream>>>(features, coords, featT,
                                                     invmap, N, tiles);

    // K2: validated gather + emit.
    pss_gather_emit_v<<<BB * NHH, 256, 0, stream>>>(featT, invmap, coords, out,
                                                    N);
}

// Round 24
// 85.729 us; speedup vs baseline: 1.2086x; 1.1071x over previous
//
#include <hip/hip_runtime.h>

// Problem constants: features [C=32, N], coords [N,3]=(b,h,w),
// output [B=64, C=32, NH=64, NW=256] float32.
#define CC 32
#define BB 64
#define NHH 64
#define NWW 256
#define PLANE (NHH * NWW)        // 16384 cells per batch
#define BSTRIDE (CC * PLANE)     // 524288 floats per batch in out
#define NCELLS (BB * PLANE)      // 1048576 total cells
#define LROW 260                 // LDS row stride (dwords); 1040B rows, 16B-aligned

typedef float f32x4 __attribute__((ext_vector_type(4)));
typedef _Float16 f16x8 __attribute__((ext_vector_type(8)));  // 16B

// ---------- Fallback (round-1) direct scatter ----------
__global__ void pss_scatter_direct(const float* __restrict__ features,
                                   const int* __restrict__ coords,
                                   float* __restrict__ out, int N) {
    int n = blockIdx.x * blockDim.x + threadIdx.x;
    if (n >= N) return;
    int b = coords[3 * n + 0];
    int h = coords[3 * n + 1];
    int w = coords[3 * n + 2];
    int base = b * BSTRIDE + h * NWW + w;
#pragma unroll
    for (int c = 0; c < CC; ++c)
        out[base + c * PLANE] = features[c * N + n];
}

// ---------- K-1: zero invmap ----------
__global__ __launch_bounds__(256) void pss_zero(int4* __restrict__ p, int n4) {
    int i = blockIdx.x * blockDim.x + threadIdx.x;
    if (i < n4) p[i] = make_int4(0, 0, 0, 0);
}

// ---------- K1: DMA-staged transpose -> f16 featT, fused invmap ----------
// features [C][N] f32 -> featT [N][C] f16 (57.6 MB staging; absmax 0.031
// vs threshold 0.108). Load phase: __builtin_amdgcn_global_load_lds width=16,
// wave-uniform base + lane*16B = lds[c*LROW], 1KB per issue, no VGPR
// roundtrip. Store phase: f16x8 pack, lanes contiguous 1KB/instr, sequential
// in n. Fused invmap scatter (random 4B into 4MB region; L3-absorbed).
// Proven best structure: r18 = 85.6us.
__global__ __launch_bounds__(256) void pss_transpose_f16_dma(
        const float* __restrict__ features, const int* __restrict__ coords,
        f16x8* __restrict__ featT, int* __restrict__ invmap, int N) {
    __shared__ float lds[CC * LROW];  // 33280 B

    int t = threadIdx.x;
    int lane = t & 63;
    int w = t >> 6;
    int n0 = blockIdx.x * 256;

    // Fused invmap scatter.
    int n = n0 + t;
    if (n < N) {
        int b = coords[3 * n + 0];
        int h = coords[3 * n + 1];
        int ww = coords[3 * n + 2];
        invmap[b * PLANE + h * NWW + ww] = n + 1;
    }

    // Load phase: wave w owns channel rows c = 8w .. 8w+7.
    if (n0 + 256 <= N) {
#pragma unroll
        for (int r = 0; r < 8; ++r) {
            int c = 8 * w + r;
            const float* gp = &features[(size_t)c * N + n0 + 4 * lane];
            __builtin_amdgcn_global_load_lds(
                (const __attribute__((address_space(1))) void*)gp,
                (__attribute__((address_space(3))) void*)&lds[c * LROW],
                16, 0, 0);
        }
    } else {
        // Tail tile: guarded path (N % 4 == 0 -> whole-quad guard).
#pragma unroll
        for (int r = 0; r < 8; ++r) {
            int c = 8 * w + r;
            int nn = n0 + 4 * lane;
            f32x4 v = (f32x4){0.f, 0.f, 0.f, 0.f};
            if (nn < N)
                v = *(const f32x4*)&features[(size_t)c * N + nn];
            *(f32x4*)&lds[c * LROW + 4 * lane] = v;
        }
    }

    __syncthreads();  // drains vmcnt(0): DMA complete, LDS visible block-wide

    // Store phase: transposed read + f16 pack + linear 16B store.
#pragma unroll
    for (int j = 0; j < 4; ++j) {
        int idx = t + 256 * j;
        int nl = idx >> 2;
        int g = idx & 3;
        if (n0 + nl < N) {
            f16x8 hv;
#pragma unroll
            for (int e = 0; e < 8; ++e)
                hv[e] = (_Float16)lds[(8 * g + e) * LROW + nl];
            featT[(size_t)n0 * 4 + idx] = hv;  // lanes contiguous, 1KB/instr
        }
    }
}

// ---------- K2: gather f16 featT rows per cell, emit out coalesced ----------
// featT rows random but L3-resident (57.6 MB). out stores nontemporal
// (write-once 128MB stream; don't evict featT/features).
__global__ __launch_bounds__(256) void pss_gather_emit_f16(
        const f16x8* __restrict__ featT, const int* __restrict__ invmap,
        float* __restrict__ out) {
    __shared__ float lds[NWW * (CC + 1)];  // 256 * 33 floats

    int row = blockIdx.x;          // 0 .. B*NH-1  (row = b*NHH + h)
    int b = row / NHH;
    int h = row % NHH;
    int t = threadIdx.x;           // 0..255 = w

    int inv = invmap[(size_t)row * NWW + t];  // coalesced 1KB per block

    if (inv > 0) {
        const f16x8* src = featT + (size_t)(inv - 1) * 4;  // 64B row = 1 line
#pragma unroll
        for (int k = 0; k < 4; ++k) {
            f16x8 hv = src[k];
#pragma unroll
            for (int e = 0; e < 8; ++e)
                lds[t * (CC + 1) + 8 * k + e] = (float)hv[e];
        }
    } else {
#pragma unroll
        for (int k = 0; k < CC; ++k)
            lds[t * (CC + 1) + k] = 0.0f;
    }

    __syncthreads();

    size_t obase = (size_t)b * BSTRIDE + (size_t)h * NWW + t;
#pragma unroll
    for (int c = 0; c < CC; ++c) {
        float v = lds[t * (CC + 1) + c];  // bank (t+c)%32 -> conflict-free
        __builtin_nontemporal_store(v, &out[obase + (size_t)c * PLANE]);
    }
}

extern "C" void kernel_launch(void* const* d_in, const int* in_sizes, int n_in,
                              void* d_out, int out_size, void* d_ws, size_t ws_size,
                              hipStream_t stream) {
    const float* features = (const float*)d_in[0];
    const int* coords = (const int*)d_in[1];
    float* out = (float*)d_out;
    const int N = in_sizes[1] / 3;

    const size_t invmap_bytes = (size_t)NCELLS * sizeof(int);        // 4 MiB
    const size_t featT_bytes = (size_t)N * CC * sizeof(_Float16);    // ~57.6 MB

    if (ws_size < invmap_bytes + featT_bytes) {
        // Fallback: direct scatter (correct, slower).
        (void)hipMemsetAsync(d_out, 0, (size_t)out_size * sizeof(float), stream);
        int blocks = (N + 255) / 256;
        pss_scatter_direct<<<blocks, 256, 0, stream>>>(features, coords, out, N);
        return;
    }

    int* invmap = (int*)d_ws;
    f16x8* featT = (f16x8*)((char*)d_ws + invmap_bytes);

    // Zero invmap (0 == empty cell).
    pss_zero<<<(NCELLS / 4 + 255) / 256, 256, 0, stream>>>((int4*)invmap,
                                                           NCELLS / 4);

    int tiles = (N + 255) / 256;
    pss_transpose_f16_dma<<<tiles, 256, 0, stream>>>(features, coords, featT,
                                                     invmap, N);

    pss_gather_emit_f16<<<BB * NHH, 256, 0, stream>>>(featT, invmap, out);
}